// Round 3
// baseline (74.704 us; speedup 1.0000x reference)
//
#include <hip/hip_runtime.h>

typedef __attribute__((ext_vector_type(8))) short bf16x8;
typedef __attribute__((ext_vector_type(4))) short bf16x4;
typedef __attribute__((ext_vector_type(4))) float f32x4;

#define B_NUM 2048
#define F_NUM 40
#define E_DIM 32
#define P_NUM 780
#define D_DIM 16
#define PC_N  65            // pair chunks
#define PC_SZ 12            // 65*12 = 780 exactly
#define LN_EPS 1e-3f

// workspace layout (bytes)
#define XB_OFF 0
#define XB_BYTES (B_NUM * F_NUM * E_DIM * 2)     // 5.24 MB bf16 x, row-major [b][f][e]
#define WF_OFF XB_BYTES
#define WF_BYTES (P_NUM * 2 * 64 * 8 * 2)        // 1.6 MB f-permuted W fragments
#define HP_OFF (WF_OFF + WF_BYTES)               // hpart f32 [PC_N][B][D] = 8.3 MB

static __device__ __forceinline__ unsigned short f2b(float f) {
  unsigned u = __builtin_bit_cast(unsigned, f);
  u += 0x7fffu + ((u >> 16) & 1u);               // round-to-nearest-even
  return (unsigned short)(u >> 16);
}
static __device__ __forceinline__ float b2f(unsigned short u) {
  return __builtin_bit_cast(float, (unsigned)u << 16);
}

// ---------------------------------------------------------------------------
// Prep: x -> bf16 row-major; W -> per-lane A-fragments with f-PERMUTED m-rows.
// A-frag layout (16x16x32): lane l holds A[m = l&15][k = (l>>4)*8 + t].
// We choose m -> f_orig = (m>>2)*8 + frag*4 + (m&3), so that the C-row
// index (m = lhi*4+r) maps to f_orig = lhi*8 + frag*4 + r: the epilogue's
// xj values for one lane are the contiguous bf16x8 at f = lhi*8.
__global__ __launch_bounds__(256) void prep_kernel(
    const float* __restrict__ x, const float* __restrict__ W,
    short* __restrict__ xb, short* __restrict__ wfrag) {
  if (blockIdx.x < 2560) {
    const size_t idx = ((size_t)blockIdx.x * 256 + threadIdx.x) * 4;
    float4 v = *reinterpret_cast<const float4*>(x + idx);
    bf16x4 o;
    o[0] = (short)f2b(v.x); o[1] = (short)f2b(v.y);
    o[2] = (short)f2b(v.z); o[3] = (short)f2b(v.w);
    *reinterpret_cast<bf16x4*>(xb + idx) = o;
  } else {
    const int p    = (blockIdx.x - 2560) * 4 + (threadIdx.x >> 6);
    const int lane = threadIdx.x & 63;
    const int lhi = lane >> 4, llo = lane & 15;
    const float* Wp = W + (size_t)p * (E_DIM * E_DIM);
#pragma unroll
    for (int frag = 0; frag < 2; ++frag) {
      const int fo = (llo >> 2) * 8 + frag * 4 + (llo & 3);   // permuted f
      bf16x8 v;
#pragma unroll
      for (int t = 0; t < 8; ++t)
        v[t] = (short)f2b(Wp[(lhi * 8 + t) * E_DIM + fo]);    // A[m][k]=W[e=k][fo]
      *reinterpret_cast<bf16x8*>(wfrag + ((size_t)(p * 2 + frag) * 64 + lane) * 8) = v;
    }
  }
}

// ---------------------------------------------------------------------------
// Fused: p = xi' W xj via MFMA, immediately folded into h += p * dense_w.
// grid (2048/256, 65), block 256 = 4 waves x 64 batches; each wave: 12 pairs.
// Per pair: 2 A-frag loads (uniform addr), 4 xj bf16x8 loads (same pattern as
// B-frag), 8 MFMA, lane-local f-partial dot + hacc FMA. No DS ops in loop.
__global__ __launch_bounds__(256) void fused_bilinear_dense_kernel(
    const short* __restrict__ xb, const short* __restrict__ wfrag,
    const float* __restrict__ dw, float* __restrict__ hpart) {
  const int lane = threadIdx.x & 63;
  const int wv   = threadIdx.x >> 6;
  const int lhi = lane >> 4, llo = lane & 15;
  const int bb = blockIdx.x * 256 + wv * 64;
  const int pc = blockIdx.y;
  const int p0 = pc * PC_SZ;

  // per-lane x row base pointers for the 4 n-tiles (bfrag & xj share pattern)
  const short* xrow[4];
#pragma unroll
  for (int nt = 0; nt < 4; ++nt)
    xrow[nt] = xb + (size_t)(bb + nt * 16 + llo) * (F_NUM * E_DIM) + lhi * 8;

  float hacc[4][D_DIM];
#pragma unroll
  for (int nt = 0; nt < 4; ++nt)
#pragma unroll
    for (int d = 0; d < D_DIM; ++d) hacc[nt][d] = 0.f;

  // locate (i,j) of pair p0 in combinations(range(40),2) order
  int i = 0;
  while ((i + 1) * (79 - (i + 1)) / 2 <= p0) ++i;
  int j = i + 1 + (p0 - i * (79 - i) / 2);

  bf16x8 bfr[4];
#pragma unroll
  for (int nt = 0; nt < 4; ++nt)
    bfr[nt] = *reinterpret_cast<const bf16x8*>(xrow[nt] + i * E_DIM);

#pragma unroll 2
  for (int p = p0; p < p0 + PC_SZ; ++p) {
    const int pu = __builtin_amdgcn_readfirstlane(p);
    const bf16x8 a0 = *reinterpret_cast<const bf16x8*>(
        wfrag + ((size_t)(pu * 2 + 0) * 64 + lane) * 8);
    const bf16x8 a1 = *reinterpret_cast<const bf16x8*>(
        wfrag + ((size_t)(pu * 2 + 1) * 64 + lane) * 8);
    const float* __restrict__ dwp = dw + pu * D_DIM;   // uniform -> s_load

    bf16x8 xj[4];
#pragma unroll
    for (int nt = 0; nt < 4; ++nt)
      xj[nt] = *reinterpret_cast<const bf16x8*>(xrow[nt] + j * E_DIM);

#pragma unroll
    for (int nt = 0; nt < 4; ++nt) {
      f32x4 z = {0.f, 0.f, 0.f, 0.f};
      f32x4 c0 = __builtin_amdgcn_mfma_f32_16x16x32_bf16(a0, bfr[nt], z, 0, 0, 0);
      f32x4 c1 = __builtin_amdgcn_mfma_f32_16x16x32_bf16(a1, bfr[nt], z, 0, 0, 0);
      // C-row m=lhi*4+r -> f_orig = lhi*8 + frag*4 + r  ==  xj[nt][frag*4+r]
      float s = 0.f;
#pragma unroll
      for (int r = 0; r < 4; ++r) {
        s = fmaf(c0[r], b2f((unsigned short)xj[nt][r]), s);
        s = fmaf(c1[r], b2f((unsigned short)xj[nt][4 + r]), s);
      }
      // fold dense layer: each lane carries a partial-over-its-f-quarter h
#pragma unroll
      for (int d = 0; d < D_DIM; ++d)
        hacc[nt][d] = fmaf(s, dwp[d], hacc[nt][d]);
    }

    if (++j == F_NUM) {
      ++i; j = i + 1;
#pragma unroll
      for (int nt = 0; nt < 4; ++nt)
        bfr[nt] = *reinterpret_cast<const bf16x8*>(xrow[nt] + i * E_DIM);
    }
  }

  // butterfly-reduce the f-quarter partials across lhi (lanes ±16, ±32)
#pragma unroll
  for (int nt = 0; nt < 4; ++nt)
#pragma unroll
    for (int d = 0; d < D_DIM; ++d) {
      float v = hacc[nt][d];
      v += __shfl_xor(v, 16);
      v += __shfl_xor(v, 32);
      hacc[nt][d] = v;
    }

  // every lane stores its d-quarter: fully coalesced 16 B per lane
  float* hp = hpart + (size_t)pc * B_NUM * D_DIM;
#pragma unroll
  for (int nt = 0; nt < 4; ++nt) {
    float4 o = make_float4(hacc[nt][lhi * 4 + 0], hacc[nt][lhi * 4 + 1],
                           hacc[nt][lhi * 4 + 2], hacc[nt][lhi * 4 + 3]);
    *reinterpret_cast<float4*>(hp + (size_t)(bb + nt * 16 + llo) * D_DIM + lhi * 4) = o;
  }
}

// ---------------------------------------------------------------------------
// Final: sum the 65 h-partials + bias, LayerNorm, write out. grid 8, block 256.
__global__ __launch_bounds__(256) void reduce_ln_kernel(
    const float* __restrict__ hpart, const float* __restrict__ bias,
    const float* __restrict__ gamma, const float* __restrict__ beta,
    float* __restrict__ out) {
  const int b = blockIdx.x * 256 + threadIdx.x;
  float h[D_DIM];
#pragma unroll
  for (int d = 0; d < D_DIM; ++d) h[d] = bias[d];
  for (int pc = 0; pc < PC_N; ++pc) {
    const float* hp = hpart + ((size_t)pc * B_NUM + b) * D_DIM;
#pragma unroll
    for (int d = 0; d < D_DIM; d += 4) {
      float4 v = *reinterpret_cast<const float4*>(hp + d);
      h[d] += v.x; h[d + 1] += v.y; h[d + 2] += v.z; h[d + 3] += v.w;
    }
  }
  float mu = 0.f;
#pragma unroll
  for (int d = 0; d < D_DIM; ++d) mu += h[d];
  mu *= (1.f / D_DIM);
  float var = 0.f;
#pragma unroll
  for (int d = 0; d < D_DIM; ++d) { float t = h[d] - mu; var = fmaf(t, t, var); }
  var *= (1.f / D_DIM);
  const float rs = rsqrtf(var + LN_EPS);
#pragma unroll
  for (int d = 0; d < D_DIM; ++d)
    out[(size_t)b * D_DIM + d] = (h[d] - mu) * rs * gamma[d] + beta[d];
}

extern "C" void kernel_launch(void* const* d_in, const int* in_sizes, int n_in,
                              void* d_out, int out_size, void* d_ws, size_t ws_size,
                              hipStream_t stream) {
  const float* x     = (const float*)d_in[0];
  const float* W     = (const float*)d_in[1];
  const float* dw    = (const float*)d_in[2];
  const float* db    = (const float*)d_in[3];
  const float* gamma = (const float*)d_in[4];
  const float* beta  = (const float*)d_in[5];
  float* out = (float*)d_out;

  short* xb    = (short*)((char*)d_ws + XB_OFF);
  short* wfrag = (short*)((char*)d_ws + WF_OFF);
  float* hpart = (float*)((char*)d_ws + HP_OFF);

  prep_kernel<<<2560 + 195, 256, 0, stream>>>(x, W, xb, wfrag);

  dim3 gA(B_NUM / 256, PC_N);
  fused_bilinear_dense_kernel<<<gA, 256, 0, stream>>>(xb, wfrag, dw, hpart);

  reduce_ln_kernel<<<B_NUM / 256, 256, 0, stream>>>(hpart, db, gamma, beta, out);
}

// Round 4
// 41.826 us; speedup vs baseline: 1.7861x; 1.7861x over previous
//
#include <hip/hip_runtime.h>

typedef __attribute__((ext_vector_type(8))) short bf16x8;
typedef __attribute__((ext_vector_type(4))) short bf16x4;
typedef __attribute__((ext_vector_type(4))) float f32x4;

#define B_NUM 2048
#define F_NUM 40
#define E_DIM 32
#define P_NUM 780
#define D_DIM 16
#define PC_N  65            // pair chunks
#define PC_SZ 12            // 65*12 = 780 exactly
#define LN_EPS 1e-3f

// workspace layout (bytes)
#define XB_OFF 0
#define XB_BYTES (B_NUM * F_NUM * E_DIM * 2)     // 5.24 MB bf16 x, row-major [b][f][e]
#define WF_OFF XB_BYTES
#define WF_BYTES (P_NUM * 2 * 64 * 8 * 2)        // 1.6 MB f-permuted W fragments
#define HP_OFF (WF_OFF + WF_BYTES)               // hpart f32 [PC_N][B][D] = 8.5 MB

static __device__ __forceinline__ unsigned short f2b(float f) {
  unsigned u = __builtin_bit_cast(unsigned, f);
  u += 0x7fffu + ((u >> 16) & 1u);               // round-to-nearest-even
  return (unsigned short)(u >> 16);
}
static __device__ __forceinline__ float b2f(unsigned short u) {
  return __builtin_bit_cast(float, (unsigned)u << 16);
}

// ---------------------------------------------------------------------------
// Prep: x -> bf16 row-major; W -> per-lane A-fragments with f-PERMUTED m-rows.
// A-frag (16x16x32): lane l holds A[m = l&15][k = (l>>4)*8 + t].
// m -> f_orig = (m>>2)*8 + frag*4 + (m&3), so C-row m=lhi*4+r maps to
// f_orig = lhi*8 + frag*4 + r: one contiguous bf16x8 of xj per lane.
__global__ __launch_bounds__(256) void prep_kernel(
    const float* __restrict__ x, const float* __restrict__ W,
    short* __restrict__ xb, short* __restrict__ wfrag) {
  if (blockIdx.x < 2560) {
    const size_t idx = ((size_t)blockIdx.x * 256 + threadIdx.x) * 4;
    float4 v = *reinterpret_cast<const float4*>(x + idx);
    bf16x4 o;
    o[0] = (short)f2b(v.x); o[1] = (short)f2b(v.y);
    o[2] = (short)f2b(v.z); o[3] = (short)f2b(v.w);
    *reinterpret_cast<bf16x4*>(xb + idx) = o;
  } else {
    const int p    = (blockIdx.x - 2560) * 4 + (threadIdx.x >> 6);
    const int lane = threadIdx.x & 63;
    const int lhi = lane >> 4, llo = lane & 15;
    const float* Wp = W + (size_t)p * (E_DIM * E_DIM);
#pragma unroll
    for (int frag = 0; frag < 2; ++frag) {
      const int fo = (llo >> 2) * 8 + frag * 4 + (llo & 3);   // permuted f
      bf16x8 v;
#pragma unroll
      for (int t = 0; t < 8; ++t)
        v[t] = (short)f2b(Wp[(lhi * 8 + t) * E_DIM + fo]);    // A[m][k]=W[e=k][fo]
      *reinterpret_cast<bf16x8*>(wfrag + ((size_t)(p * 2 + frag) * 64 + lane) * 8) = v;
    }
  }
}

// ---------------------------------------------------------------------------
// Fused: p = xi' W xj via MFMA, shuffle-completed, folded into h += p * dw[p].
// grid (2048/128, 65), block 256 = 4 waves; wave = 32 batches (2 n-tiles),
// 12 pairs. All register arrays statically indexed (no scratch).
__global__ __launch_bounds__(256, 4) void fused_bilinear_dense_kernel(
    const short* __restrict__ xb, const short* __restrict__ wfrag,
    const float* __restrict__ dw, float* __restrict__ hpart) {
  const int lane = threadIdx.x & 63;
  const int wv   = threadIdx.x >> 6;
  const int lhi = lane >> 4, llo = lane & 15;
  const int bb = blockIdx.x * 128 + wv * 32;
  const int pc = blockIdx.y;
  const int p0 = pc * PC_SZ;

  const short* xrow0 = xb + (size_t)(bb + llo) * (F_NUM * E_DIM) + lhi * 8;
  const short* xrow1 = xrow0 + 16 * (F_NUM * E_DIM);

  float h00 = 0.f, h01 = 0.f, h02 = 0.f, h03 = 0.f;   // nt=0, d = lhi*4+q
  float h10 = 0.f, h11 = 0.f, h12 = 0.f, h13 = 0.f;   // nt=1

  // locate (i,j) of pair p0 in combinations(range(40),2) order
  int i = 0;
  while ((i + 1) * (79 - (i + 1)) / 2 <= p0) ++i;
  int j = i + 1 + (p0 - i * (79 - i) / 2);

  bf16x8 bf0 = *reinterpret_cast<const bf16x8*>(xrow0 + i * E_DIM);
  bf16x8 bf1 = *reinterpret_cast<const bf16x8*>(xrow1 + i * E_DIM);

#pragma unroll 2
  for (int p = p0; p < p0 + PC_SZ; ++p) {
    const bf16x8 a0 = *reinterpret_cast<const bf16x8*>(
        wfrag + ((size_t)(p * 2 + 0) * 64 + lane) * 8);
    const bf16x8 a1 = *reinterpret_cast<const bf16x8*>(
        wfrag + ((size_t)(p * 2 + 1) * 64 + lane) * 8);
    const float4 dwq = *reinterpret_cast<const float4*>(dw + p * D_DIM + lhi * 4);
    const bf16x8 xj0 = *reinterpret_cast<const bf16x8*>(xrow0 + j * E_DIM);
    const bf16x8 xj1 = *reinterpret_cast<const bf16x8*>(xrow1 + j * E_DIM);

    f32x4 z = {0.f, 0.f, 0.f, 0.f};
    f32x4 c00 = __builtin_amdgcn_mfma_f32_16x16x32_bf16(a0, bf0, z, 0, 0, 0);
    f32x4 c01 = __builtin_amdgcn_mfma_f32_16x16x32_bf16(a1, bf0, z, 0, 0, 0);
    f32x4 c10 = __builtin_amdgcn_mfma_f32_16x16x32_bf16(a0, bf1, z, 0, 0, 0);
    f32x4 c11 = __builtin_amdgcn_mfma_f32_16x16x32_bf16(a1, bf1, z, 0, 0, 0);

    float s0 = 0.f, s1 = 0.f;
#pragma unroll
    for (int r = 0; r < 4; ++r) {
      s0 = fmaf(c00[r], b2f((unsigned short)xj0[r]), s0);
      s0 = fmaf(c01[r], b2f((unsigned short)xj0[4 + r]), s0);
      s1 = fmaf(c10[r], b2f((unsigned short)xj1[r]), s1);
      s1 = fmaf(c11[r], b2f((unsigned short)xj1[4 + r]), s1);
    }
    // complete p across the 4 f-quarters (lhi groups)
    s0 += __shfl_xor(s0, 16); s0 += __shfl_xor(s0, 32);
    s1 += __shfl_xor(s1, 16); s1 += __shfl_xor(s1, 32);

    // fold dense: this lane owns d-quad lhi*4..lhi*4+3 (static indices only)
    h00 = fmaf(s0, dwq.x, h00); h01 = fmaf(s0, dwq.y, h01);
    h02 = fmaf(s0, dwq.z, h02); h03 = fmaf(s0, dwq.w, h03);
    h10 = fmaf(s1, dwq.x, h10); h11 = fmaf(s1, dwq.y, h11);
    h12 = fmaf(s1, dwq.z, h12); h13 = fmaf(s1, dwq.w, h13);

    if (++j == F_NUM) {
      ++i; j = i + 1;
      bf0 = *reinterpret_cast<const bf16x8*>(xrow0 + i * E_DIM);
      bf1 = *reinterpret_cast<const bf16x8*>(xrow1 + i * E_DIM);
    }
  }

  // coalesced stores: per nt, wave covers 16 batches x 16 d = 1 KB contiguous
  float* hp = hpart + (size_t)pc * B_NUM * D_DIM;
  *reinterpret_cast<float4*>(hp + (size_t)(bb + llo) * D_DIM + lhi * 4) =
      make_float4(h00, h01, h02, h03);
  *reinterpret_cast<float4*>(hp + (size_t)(bb + 16 + llo) * D_DIM + lhi * 4) =
      make_float4(h10, h11, h12, h13);
}

// ---------------------------------------------------------------------------
// Final: sum 65 h-partials + bias, LayerNorm. grid 128, block 256;
// thread = (b, d): coalesced 1 KB/iter, LN via shfl within 16-lane groups.
__global__ __launch_bounds__(256) void reduce_ln_kernel(
    const float* __restrict__ hpart, const float* __restrict__ bias,
    const float* __restrict__ gamma, const float* __restrict__ beta,
    float* __restrict__ out) {
  const int t = threadIdx.x;
  const int d = t & 15;
  const int b = blockIdx.x * 16 + (t >> 4);
  float acc = bias[d];
  const float* hp = hpart + (size_t)b * D_DIM + d;
#pragma unroll 5
  for (int pc = 0; pc < PC_N; ++pc)
    acc += hp[(size_t)pc * B_NUM * D_DIM];

  float sum = acc;
  sum += __shfl_xor(sum, 1); sum += __shfl_xor(sum, 2);
  sum += __shfl_xor(sum, 4); sum += __shfl_xor(sum, 8);
  const float mu = sum * (1.f / D_DIM);
  const float dev = acc - mu;
  float v = dev * dev;
  v += __shfl_xor(v, 1); v += __shfl_xor(v, 2);
  v += __shfl_xor(v, 4); v += __shfl_xor(v, 8);
  const float rs = rsqrtf(v * (1.f / D_DIM) + LN_EPS);
  out[(size_t)b * D_DIM + d] = dev * rs * gamma[d] + beta[d];
}

extern "C" void kernel_launch(void* const* d_in, const int* in_sizes, int n_in,
                              void* d_out, int out_size, void* d_ws, size_t ws_size,
                              hipStream_t stream) {
  const float* x     = (const float*)d_in[0];
  const float* W     = (const float*)d_in[1];
  const float* dw    = (const float*)d_in[2];
  const float* db    = (const float*)d_in[3];
  const float* gamma = (const float*)d_in[4];
  const float* beta  = (const float*)d_in[5];
  float* out = (float*)d_out;

  short* xb    = (short*)((char*)d_ws + XB_OFF);
  short* wfrag = (short*)((char*)d_ws + WF_OFF);
  float* hpart = (float*)((char*)d_ws + HP_OFF);

  prep_kernel<<<2560 + 195, 256, 0, stream>>>(x, W, xb, wfrag);

  dim3 gA(B_NUM / 128, PC_N);
  fused_bilinear_dense_kernel<<<gA, 256, 0, stream>>>(xb, wfrag, dw, hpart);

  reduce_ln_kernel<<<B_NUM / 16, 256, 0, stream>>>(hpart, db, gamma, beta, out);
}

// Round 5
// 40.226 us; speedup vs baseline: 1.8571x; 1.0398x over previous
//
#include <hip/hip_runtime.h>

typedef __attribute__((ext_vector_type(8))) short bf16x8;
typedef __attribute__((ext_vector_type(4))) short bf16x4;
typedef __attribute__((ext_vector_type(4))) float f32x4;

#define B_NUM 2048
#define F_NUM 40
#define E_DIM 32
#define P_NUM 780
#define D_DIM 16
#define PC_N  65            // pair chunks
#define PC_SZ 12            // 65*12 = 780 exactly
#define LN_EPS 1e-3f

// workspace layout (bytes)
#define XB_OFF 0
#define XB_BYTES (B_NUM * F_NUM * E_DIM * 2)     // 5.24 MB bf16 x, row-major [b][f][e]
#define WF_OFF XB_BYTES
#define WF_BYTES (P_NUM * 2 * 64 * 8 * 2)        // 1.6 MB f-permuted W fragments
#define HP_OFF (WF_OFF + WF_BYTES)               // hpart f32 [PC_N][B][D] = 8.5 MB

static __device__ __forceinline__ unsigned short f2b(float f) {
  unsigned u = __builtin_bit_cast(unsigned, f);
  u += 0x7fffu + ((u >> 16) & 1u);               // round-to-nearest-even
  return (unsigned short)(u >> 16);
}
static __device__ __forceinline__ float b2f(unsigned short u) {
  return __builtin_bit_cast(float, (unsigned)u << 16);
}

// ---------------------------------------------------------------------------
// Prep: x -> bf16 row-major; W -> per-lane A-fragments with f-PERMUTED m-rows.
// A-frag (16x16x32): lane l holds A[m = l&15][k = (l>>4)*8 + t].
// m -> f_orig = (m>>2)*8 + frag*4 + (m&3), so C-row m=lhi*4+r maps to
// f_orig = lhi*8 + frag*4 + r: one contiguous bf16x8 of xj per lane.
// W gather goes through LDS: coalesced global reads, cheap LDS transpose.
__global__ __launch_bounds__(256) void prep_kernel(
    const float* __restrict__ x, const float* __restrict__ W,
    short* __restrict__ xb, short* __restrict__ wfrag) {
  const int lane = threadIdx.x & 63;
  const int wv   = threadIdx.x >> 6;
  const int lhi = lane >> 4, llo = lane & 15;
  __shared__ float wst[4][E_DIM * E_DIM];        // 16 KB, one W_p per wave

  if (blockIdx.x < 2560) {
    const size_t idx = ((size_t)blockIdx.x * 256 + threadIdx.x) * 4;
    float4 v = *reinterpret_cast<const float4*>(x + idx);
    bf16x4 o;
    o[0] = (short)f2b(v.x); o[1] = (short)f2b(v.y);
    o[2] = (short)f2b(v.z); o[3] = (short)f2b(v.w);
    *reinterpret_cast<bf16x4*>(xb + idx) = o;
  } else {
    const int p = (blockIdx.x - 2560) * 4 + wv;
    const float* Wp = W + (size_t)p * (E_DIM * E_DIM);
    // stage W_p (4 KB) into this wave's LDS slab: 4 coalesced float4 per lane
#pragma unroll
    for (int k = 0; k < 4; ++k) {
      float4 v = *reinterpret_cast<const float4*>(Wp + k * 256 + lane * 4);
      *reinterpret_cast<float4*>(&wst[wv][k * 256 + lane * 4]) = v;
    }
    // same-wave LDS RAW: compiler inserts lgkmcnt wait, no barrier needed
#pragma unroll
    for (int frag = 0; frag < 2; ++frag) {
      const int fo = (llo >> 2) * 8 + frag * 4 + (llo & 3);   // permuted f
      bf16x8 v;
#pragma unroll
      for (int t = 0; t < 8; ++t)
        v[t] = (short)f2b(wst[wv][(lhi * 8 + t) * E_DIM + fo]);
      *reinterpret_cast<bf16x8*>(wfrag + ((size_t)(p * 2 + frag) * 64 + lane) * 8) = v;
    }
  }
}

// ---------------------------------------------------------------------------
// Fused: p = xi' W xj via MFMA, shuffle-completed, folded into h += p * dw[p].
// grid (2048/128, 65), block 256 = 4 waves; wave = 32 batches (2 n-tiles).
// A-fragments for the chunk's 12 pairs are LDS-staged once per block (24 KB),
// shared by all 4 waves; inner-loop global traffic is xj + dw only.
__global__ __launch_bounds__(256, 4) void fused_bilinear_dense_kernel(
    const short* __restrict__ xb, const short* __restrict__ wfrag,
    const float* __restrict__ dw, float* __restrict__ hpart) {
  __shared__ short alds[PC_SZ * 2 * 512];        // 24 KB: [seg=pl*2+frag][lane][8]
  const int lane = threadIdx.x & 63;
  const int wv   = threadIdx.x >> 6;
  const int lhi = lane >> 4, llo = lane & 15;
  const int bb = blockIdx.x * 128 + wv * 32;
  const int pc = blockIdx.y;
  const int p0 = pc * PC_SZ;

  // stage: wave wv copies segments [6wv, 6wv+6) (1 KB each, lane*16B layout)
#pragma unroll
  for (int s = 0; s < 6; ++s) {
    const int seg = wv * 6 + s;                  // = pl*2 + frag
    bf16x8 v = *reinterpret_cast<const bf16x8*>(
        wfrag + ((size_t)(p0 * 2 + seg) * 64 + lane) * 8);
    *reinterpret_cast<bf16x8*>(&alds[seg * 512 + lane * 8]) = v;  // ds_write_b128
  }
  __syncthreads();

  const short* xrow0 = xb + (size_t)(bb + llo) * (F_NUM * E_DIM) + lhi * 8;
  const short* xrow1 = xrow0 + 16 * (F_NUM * E_DIM);

  float h00 = 0.f, h01 = 0.f, h02 = 0.f, h03 = 0.f;   // nt=0, d = lhi*4+q
  float h10 = 0.f, h11 = 0.f, h12 = 0.f, h13 = 0.f;   // nt=1

  // locate (i,j) of pair p0 in combinations(range(40),2) order
  int i = 0;
  while ((i + 1) * (79 - (i + 1)) / 2 <= p0) ++i;
  int j = i + 1 + (p0 - i * (79 - i) / 2);

  bf16x8 bf0 = *reinterpret_cast<const bf16x8*>(xrow0 + i * E_DIM);
  bf16x8 bf1 = *reinterpret_cast<const bf16x8*>(xrow1 + i * E_DIM);

#pragma unroll 2
  for (int pl = 0; pl < PC_SZ; ++pl) {
    const int p = p0 + pl;
    const bf16x8 a0 = *reinterpret_cast<const bf16x8*>(&alds[(pl * 2 + 0) * 512 + lane * 8]);
    const bf16x8 a1 = *reinterpret_cast<const bf16x8*>(&alds[(pl * 2 + 1) * 512 + lane * 8]);
    const float4 dwq = *reinterpret_cast<const float4*>(dw + p * D_DIM + lhi * 4);
    const bf16x8 xj0 = *reinterpret_cast<const bf16x8*>(xrow0 + j * E_DIM);
    const bf16x8 xj1 = *reinterpret_cast<const bf16x8*>(xrow1 + j * E_DIM);

    f32x4 z = {0.f, 0.f, 0.f, 0.f};
    f32x4 c00 = __builtin_amdgcn_mfma_f32_16x16x32_bf16(a0, bf0, z, 0, 0, 0);
    f32x4 c01 = __builtin_amdgcn_mfma_f32_16x16x32_bf16(a1, bf0, z, 0, 0, 0);
    f32x4 c10 = __builtin_amdgcn_mfma_f32_16x16x32_bf16(a0, bf1, z, 0, 0, 0);
    f32x4 c11 = __builtin_amdgcn_mfma_f32_16x16x32_bf16(a1, bf1, z, 0, 0, 0);

    float s0 = 0.f, s1 = 0.f;
#pragma unroll
    for (int r = 0; r < 4; ++r) {
      s0 = fmaf(c00[r], b2f((unsigned short)xj0[r]), s0);
      s0 = fmaf(c01[r], b2f((unsigned short)xj0[4 + r]), s0);
      s1 = fmaf(c10[r], b2f((unsigned short)xj1[r]), s1);
      s1 = fmaf(c11[r], b2f((unsigned short)xj1[4 + r]), s1);
    }
    // complete p across the 4 f-quarters (lhi groups)
    s0 += __shfl_xor(s0, 16); s0 += __shfl_xor(s0, 32);
    s1 += __shfl_xor(s1, 16); s1 += __shfl_xor(s1, 32);

    // fold dense: this lane owns d-quad lhi*4..lhi*4+3 (static indices only)
    h00 = fmaf(s0, dwq.x, h00); h01 = fmaf(s0, dwq.y, h01);
    h02 = fmaf(s0, dwq.z, h02); h03 = fmaf(s0, dwq.w, h03);
    h10 = fmaf(s1, dwq.x, h10); h11 = fmaf(s1, dwq.y, h11);
    h12 = fmaf(s1, dwq.z, h12); h13 = fmaf(s1, dwq.w, h13);

    if (++j == F_NUM) {
      ++i; j = i + 1;
      bf0 = *reinterpret_cast<const bf16x8*>(xrow0 + i * E_DIM);
      bf1 = *reinterpret_cast<const bf16x8*>(xrow1 + i * E_DIM);
    }
  }

  // coalesced stores: per nt, wave covers 16 batches x 16 d = 1 KB contiguous
  float* hp = hpart + (size_t)pc * B_NUM * D_DIM;
  *reinterpret_cast<float4*>(hp + (size_t)(bb + llo) * D_DIM + lhi * 4) =
      make_float4(h00, h01, h02, h03);
  *reinterpret_cast<float4*>(hp + (size_t)(bb + 16 + llo) * D_DIM + lhi * 4) =
      make_float4(h10, h11, h12, h13);
}

// ---------------------------------------------------------------------------
// Final: sum 65 h-partials + bias, LayerNorm. grid 128, block 256;
// thread = (b, d): coalesced 1 KB/iter, LN via shfl within 16-lane groups.
__global__ __launch_bounds__(256) void reduce_ln_kernel(
    const float* __restrict__ hpart, const float* __restrict__ bias,
    const float* __restrict__ gamma, const float* __restrict__ beta,
    float* __restrict__ out) {
  const int t = threadIdx.x;
  const int d = t & 15;
  const int b = blockIdx.x * 16 + (t >> 4);
  float acc = bias[d];
  const float* hp = hpart + (size_t)b * D_DIM + d;
#pragma unroll 5
  for (int pc = 0; pc < PC_N; ++pc)
    acc += hp[(size_t)pc * B_NUM * D_DIM];

  float sum = acc;
  sum += __shfl_xor(sum, 1); sum += __shfl_xor(sum, 2);
  sum += __shfl_xor(sum, 4); sum += __shfl_xor(sum, 8);
  const float mu = sum * (1.f / D_DIM);
  const float dev = acc - mu;
  float v = dev * dev;
  v += __shfl_xor(v, 1); v += __shfl_xor(v, 2);
  v += __shfl_xor(v, 4); v += __shfl_xor(v, 8);
  const float rs = rsqrtf(v * (1.f / D_DIM) + LN_EPS);
  out[(size_t)b * D_DIM + d] = dev * rs * gamma[d] + beta[d];
}

extern "C" void kernel_launch(void* const* d_in, const int* in_sizes, int n_in,
                              void* d_out, int out_size, void* d_ws, size_t ws_size,
                              hipStream_t stream) {
  const float* x     = (const float*)d_in[0];
  const float* W     = (const float*)d_in[1];
  const float* dw    = (const float*)d_in[2];
  const float* db    = (const float*)d_in[3];
  const float* gamma = (const float*)d_in[4];
  const float* beta  = (const float*)d_in[5];
  float* out = (float*)d_out;

  short* xb    = (short*)((char*)d_ws + XB_OFF);
  short* wfrag = (short*)((char*)d_ws + WF_OFF);
  float* hpart = (float*)((char*)d_ws + HP_OFF);

  prep_kernel<<<2560 + 195, 256, 0, stream>>>(x, W, xb, wfrag);

  dim3 gA(B_NUM / 128, PC_N);
  fused_bilinear_dense_kernel<<<gA, 256, 0, stream>>>(xb, wfrag, dw, hpart);

  reduce_ln_kernel<<<B_NUM / 16, 256, 0, stream>>>(hpart, db, gamma, beta, out);
}